// Round 7
// baseline (466.874 us; speedup 1.0000x reference)
//
#include <hip/hip_runtime.h>
#include <math.h>

#define BB 2
#define CC 512
#define HEADS 2
#define DH 256
#define NWIN 64
#define LTOT 4096
#define TP 3
#define LP 3
#define SCALE 0.0625f

typedef short bf16x8 __attribute__((ext_vector_type(8)));
typedef float f32x4 __attribute__((ext_vector_type(4)));

__device__ __forceinline__ int refl8(int v) {
  v = v < 0 ? -v : v;
  return v >= 8 ? 14 - v : v;
}

__device__ __forceinline__ unsigned int bf16rne(float x) {
  unsigned int u = __float_as_uint(x);
  return (u + 0x7fffu + ((u >> 16) & 1u)) >> 16;
}

__device__ __forceinline__ float bf2f(unsigned short u) {
  return __uint_as_float(((unsigned int)u) << 16);
}

// Both 1x1 convs in one launch. Y[b,o,p] = sum_c W[o,c] X[b,c,p] + bias[o]
__global__ __launch_bounds__(256) void conv_both_kernel(
    const float* __restrict__ X1, const float* __restrict__ W1,
    const float* __restrict__ b1, float* __restrict__ Y1,
    const float* __restrict__ X2, const float* __restrict__ W2,
    const float* __restrict__ b2, float* __restrict__ Y2) {
  int bidx = blockIdx.x;
  const float *X, *Wm, *bias;
  float* Y;
  int Cout;
  if (bidx < BB * (1536 / 4)) {
    X = X1; Wm = W1; bias = b1; Y = Y1; Cout = 1536;
  } else {
    bidx -= BB * (1536 / 4);
    X = X2; Wm = W2; bias = b2; Y = Y2; Cout = 1024;
  }
  int blocksPerB = Cout >> 2;
  int b = bidx / blocksPerB;
  int ob = bidx - b * blocksPerB;
  int o = ob * 4 + (threadIdx.x >> 6);
  int p = threadIdx.x & 63;
  const float* xb = X + (size_t)b * CC * 64;
  const float* wr = Wm + (size_t)o * CC;
  float acc = 0.f;
#pragma unroll 8
  for (int c = 0; c < CC; ++c) acc += wr[c] * xb[c * 64 + p];
  Y[((size_t)b * Cout + o) * 64 + p] = acc + bias[o];
}

// One block per (b, win, head). Local window attention.
// Emits qgb (B,h,L,d) row-major bf16 AND qgT (B,h,d,L) dim-major bf16.
__global__ __launch_bounds__(256) void local_attn_kernel(
    const float* __restrict__ qkvx, const float* __restrict__ qkz,
    const float* __restrict__ pbeta, unsigned short* __restrict__ qgb,
    unsigned short* __restrict__ qgT) {
  __shared__ float kbuf[64 * 132];  // reused: K phases [dd][tok], AV phase [tok][dim]
  __shared__ float att[64 * 65];
  __shared__ float red[4 * 64];
  int bid = blockIdx.x;
  int b = bid >> 7;
  int win = (bid & 127) >> 1;
  int head = bid & 1;
  int tid = threadIdx.x;
  int t = tid & 63;
  int w4 = tid >> 6;
  int wi = win >> 3, wj = win & 7;
  int ry = refl8(wi + (t >> 3) - TP);
  int rx = refl8(wj + (t & 7) - LP);
  int pix = ry * 8 + rx;
  float beta = log1pf(__expf(pbeta[0])) + 1e-6f;

  const float* qxb = qkvx + (size_t)(b * 1536 + head * DH) * 64;
  const float* kxb = qkvx + (size_t)(b * 1536 + 512 + head * DH) * 64;
  const float* vxb = qkvx + (size_t)(b * 1536 + 1024 + head * DH) * 64;
  const float* qzb = qkz + (size_t)(b * 1024 + head * DH) * 64;
  const float* kzb = qkz + (size_t)(b * 1024 + 512 + head * DH) * 64;

  float dots[16];
#pragma unroll
  for (int s = 0; s < 16; ++s) dots[s] = 0.f;
#pragma unroll
  for (int hf = 0; hf < 2; ++hf) {
    __syncthreads();
    for (int i = 0; i < 32; ++i) {
      int dd = i * 4 + w4;
      kbuf[dd * 64 + t] = kxb[(hf * 128 + dd) * 64 + pix];
    }
    __syncthreads();
    for (int dd = 0; dd < 128; ++dd) {
      float qv = qxb[(hf * 128 + dd) * 64 + pix];
#pragma unroll
      for (int s = 0; s < 16; ++s)
        dots[s] += qv * kbuf[dd * 64 + w4 * 16 + s];
    }
  }
#pragma unroll
  for (int s = 0; s < 16; ++s) att[t * 65 + w4 * 16 + s] = dots[s];
#pragma unroll
  for (int s = 0; s < 16; ++s) dots[s] = 0.f;
#pragma unroll
  for (int hf = 0; hf < 2; ++hf) {
    __syncthreads();
    for (int i = 0; i < 32; ++i) {
      int dd = i * 4 + w4;
      kbuf[dd * 64 + t] = kzb[(hf * 128 + dd) * 64 + pix];
    }
    __syncthreads();
    for (int dd = 0; dd < 128; ++dd) {
      float qv = qzb[(hf * 128 + dd) * 64 + pix];
#pragma unroll
      for (int s = 0; s < 16; ++s)
        dots[s] += qv * kbuf[dd * 64 + w4 * 16 + s];
    }
  }
  float vals[16];
  __syncthreads();
#pragma unroll
  for (int s = 0; s < 16; ++s)
    vals[s] = SCALE * (att[t * 65 + w4 * 16 + s] + beta * dots[s]);
  float mymax = -1e30f;
#pragma unroll
  for (int s = 0; s < 16; ++s) mymax = fmaxf(mymax, vals[s]);
  red[w4 * 64 + t] = mymax;
  __syncthreads();
  float m = fmaxf(fmaxf(red[t], red[64 + t]), fmaxf(red[128 + t], red[192 + t]));
  float mysum = 0.f;
#pragma unroll
  for (int s = 0; s < 16; ++s) {
    float e = __expf(vals[s] - m);
    vals[s] = e;
    mysum += e;
  }
  __syncthreads();
  red[w4 * 64 + t] = mysum;
  __syncthreads();
  float den = red[t] + red[64 + t] + red[128 + t] + red[192 + t];
  float rr = 1.f / den;
#pragma unroll
  for (int s = 0; s < 16; ++s) att[t * 65 + w4 * 16 + s] = vals[s] * rr;

  float acc[64];
#pragma unroll
  for (int j = 0; j < 64; ++j) acc[j] = 0.f;
#pragma unroll
  for (int hf = 0; hf < 2; ++hf) {
    __syncthreads();
    for (int i = 0; i < 32; ++i) {
      int dd = i * 4 + w4;
      kbuf[t * 132 + dd] = vxb[(hf * 128 + dd) * 64 + pix];
    }
    __syncthreads();
    for (int s = 0; s < 64; ++s) {
      float av = att[t * 65 + s];
      const float4* vrow = (const float4*)&kbuf[s * 132 + w4 * 32];
#pragma unroll
      for (int j = 0; j < 8; ++j) {
        float4 vv = vrow[j];
        acc[hf * 32 + j * 4 + 0] += av * vv.x;
        acc[hf * 32 + j * 4 + 1] += av * vv.y;
        acc[hf * 32 + j * 4 + 2] += av * vv.z;
        acc[hf * 32 + j * 4 + 3] += av * vv.w;
      }
    }
  }
  int bh = b * HEADS + head;
  unsigned short* dst = qgb + ((size_t)(bh * LTOT + win * 64 + t)) * DH;
  unsigned short* dstT = qgT + (size_t)bh * DH * LTOT + (size_t)win * 64 + t;
#pragma unroll
  for (int j = 0; j < 32; ++j) {
    int d0 = w4 * 32 + j;
    unsigned short v0 = (unsigned short)bf16rne(acc[j]);
    unsigned short v1 = (unsigned short)bf16rne(acc[32 + j]);
    dst[d0] = v0;
    dst[128 + d0] = v1;
    dstT[(size_t)d0 * LTOT] = v0;
    dstT[(size_t)(128 + d0) * LTOT] = v1;
  }
}

// Global flash attention, split-K 2-way, 4 waves/block, 16 q/wave.
// K: double-buffered LDS (reg-staged, XOR swizzle), ONE barrier per tile.
// V: read directly from global qgT in fragment layout (no LDS).
__global__ __launch_bounds__(256) void gattn_mfma(
    const unsigned short* __restrict__ qgb, const unsigned short* __restrict__ qgT,
    unsigned short* __restrict__ ogp, float2* __restrict__ ml) {
  __shared__ unsigned short kbuf[2][32 * 256];  // 2 x 16 KB double buffer
  __shared__ unsigned short plds[4 * 16 * 40];  // per-wave P, 80 B stride
  int bid = blockIdx.x;
  int split = bid & 1;
  int qt = (bid >> 1) & 63;
  int bh = bid >> 7;
  int kt0 = split * 64;
  int tid = threadIdx.x;
  int wave = tid >> 6;
  int lane = tid & 63;
  int lrow = lane & 15;
  int g = lane >> 4;
  const unsigned short* base = qgb + (size_t)bh * LTOT * DH;
  const unsigned short* baseT = qgT + (size_t)bh * DH * LTOT;
  char* plc = (char*)plds + wave * 16 * 80;

  int qi = qt * 64 + wave * 16 + lrow;
  bf16x8 qf[8];
#pragma unroll
  for (int s = 0; s < 8; ++s)
    qf[s] = *(const bf16x8*)(base + (size_t)qi * DH + s * 32 + g * 8);

  f32x4 acc[16];
#pragma unroll
  for (int f = 0; f < 16; ++f) acc[f] = (f32x4){0.f, 0.f, 0.f, 0.f};
  float m = -1e30f, l = 0.f;

  uint4 kr0, kr1, kr2, kr3;
  int skey = tid >> 5;  // 0..7
  int sdb = tid & 31;

#define KLOAD(KT)                                                \
  {                                                              \
    const unsigned short* kb = base + (size_t)(KT) * 32 * DH;    \
    kr0 = *(const uint4*)(kb + (skey + 0) * DH + sdb * 8);       \
    kr1 = *(const uint4*)(kb + (skey + 8) * DH + sdb * 8);       \
    kr2 = *(const uint4*)(kb + (skey + 16) * DH + sdb * 8);      \
    kr3 = *(const uint4*)(kb + (skey + 24) * DH + sdb * 8);      \
  }

  KLOAD(kt0);
  int cur = 0;
  for (int it = 0; it < 64; ++it) {
    int kt = kt0 + it;
    char* kc = (char*)kbuf[cur];
    // ---- write staged K -> LDS buffer `cur` (swizzled) ----
    *(uint4*)(kc + (skey + 0) * 512 + ((sdb * 16) ^ (((skey + 0) & 7) << 4))) = kr0;
    *(uint4*)(kc + (skey + 8) * 512 + ((sdb * 16) ^ (((skey + 8) & 7) << 4))) = kr1;
    *(uint4*)(kc + (skey + 16) * 512 + ((sdb * 16) ^ (((skey + 16) & 7) << 4))) = kr2;
    *(uint4*)(kc + (skey + 24) * 512 + ((sdb * 16) ^ (((skey + 24) & 7) << 4))) = kr3;
    // ---- prefetch next K tile into regs ----
    if (it + 1 < 64) KLOAD(kt + 1);
    __syncthreads();  // kbuf[cur] visible; everyone done reading kbuf[cur^1]
    // ---- S^T = K * Q^T (16 MFMAs, 4 independent chains) ----
    f32x4 s0a = (f32x4){0.f, 0.f, 0.f, 0.f}, s0b = s0a, s1a = s0a, s1b = s0a;
    int key0 = lrow, key1 = 16 + lrow;
    int sw = (lrow & 7) << 4;
    __builtin_amdgcn_s_setprio(1);
#pragma unroll
    for (int s = 0; s < 4; ++s) {
      bf16x8 k0 = *(const bf16x8*)(kc + key0 * 512 + ((g * 16 + 64 * s) ^ sw));
      s0a = __builtin_amdgcn_mfma_f32_16x16x32_bf16(k0, qf[s], s0a, 0, 0, 0);
      bf16x8 k0b = *(const bf16x8*)(kc + key0 * 512 + ((g * 16 + 64 * (s + 4)) ^ sw));
      s0b = __builtin_amdgcn_mfma_f32_16x16x32_bf16(k0b, qf[s + 4], s0b, 0, 0, 0);
      bf16x8 k1 = *(const bf16x8*)(kc + key1 * 512 + ((g * 16 + 64 * s) ^ sw));
      s1a = __builtin_amdgcn_mfma_f32_16x16x32_bf16(k1, qf[s], s1a, 0, 0, 0);
      bf16x8 k1b = *(const bf16x8*)(kc + key1 * 512 + ((g * 16 + 64 * (s + 4)) ^ sw));
      s1b = __builtin_amdgcn_mfma_f32_16x16x32_bf16(k1b, qf[s + 4], s1b, 0, 0, 0);
    }
    __builtin_amdgcn_s_setprio(0);
    // ---- issue V fragment loads from global (latency hides under softmax) ----
    bf16x8 vf[16];
    {
      const unsigned short* vrow = baseT + (size_t)lrow * LTOT + (size_t)kt * 32 + g * 8;
#pragma unroll
      for (int f = 0; f < 16; ++f)
        vf[f] = *(const bf16x8*)(vrow + (size_t)(f * 16) * LTOT);
    }
    f32x4 st0 = s0a + s0b;
    f32x4 st1 = s1a + s1b;
    // ---- online softmax with deferred rescale (thr=6) ----
    float tmax = -1e30f;
#pragma unroll
    for (int r = 0; r < 4; ++r) {
      tmax = fmaxf(tmax, st0[r]);
      tmax = fmaxf(tmax, st1[r]);
    }
    tmax = fmaxf(tmax, __shfl_xor(tmax, 16, 64));
    tmax = fmaxf(tmax, __shfl_xor(tmax, 32, 64));
    float sm = tmax * SCALE;
    if (__any(sm > m + 6.f)) {
      float mn = fmaxf(m, sm);
      float corr = __expf(m - mn);
#pragma unroll
      for (int f = 0; f < 16; ++f) {
        acc[f][0] *= corr; acc[f][1] *= corr;
        acc[f][2] *= corr; acc[f][3] *= corr;
      }
      l *= corr;
      m = mn;
    }
    float p[8];
    float psum = 0.f;
#pragma unroll
    for (int r = 0; r < 4; ++r) {
      p[r] = __expf(st0[r] * SCALE - m);
      p[4 + r] = __expf(st1[r] * SCALE - m);
      psum += p[r] + p[4 + r];
    }
    psum += __shfl_xor(psum, 16, 64);
    psum += __shfl_xor(psum, 32, 64);
    l += psum;
    // ---- write P^T (bf16) to per-wave LDS: plds[query][key] ----
    {
      uint2 pk0, pk1;
      pk0.x = bf16rne(p[0]) | (bf16rne(p[1]) << 16);
      pk0.y = bf16rne(p[2]) | (bf16rne(p[3]) << 16);
      pk1.x = bf16rne(p[4]) | (bf16rne(p[5]) << 16);
      pk1.y = bf16rne(p[6]) | (bf16rne(p[7]) << 16);
      *(uint2*)(plc + lrow * 80 + g * 8) = pk0;
      *(uint2*)(plc + lrow * 80 + 32 + g * 8) = pk1;
    }
    asm volatile("s_waitcnt lgkmcnt(0)" ::: "memory");
    // ---- O^T += V^T * P (16 MFMAs) ----
    bf16x8 pf = *(const bf16x8*)(plc + lrow * 80 + g * 16);
    __builtin_amdgcn_s_setprio(1);
#pragma unroll
    for (int f = 0; f < 16; ++f)
      acc[f] = __builtin_amdgcn_mfma_f32_16x16x32_bf16(vf[f], pf, acc[f], 0, 0, 0);
    __builtin_amdgcn_s_setprio(0);
    cur ^= 1;
  }
#undef KLOAD
  // ---- epilogue: store unnormalized partial O as bf16 + (m,l) ----
  unsigned short* dstp = ogp + ((size_t)(split * 4 + bh) * LTOT + qi) * DH;
#pragma unroll
  for (int f = 0; f < 16; ++f) {
    uint2 pk;
    pk.x = bf16rne(acc[f][0]) | (bf16rne(acc[f][1]) << 16);
    pk.y = bf16rne(acc[f][2]) | (bf16rne(acc[f][3]) << 16);
    *(uint2*)(dstp + f * 16 + g * 4) = pk;
  }
  if (g == 0) ml[(size_t)(split * 4 + bh) * LTOT + qi] = make_float2(m, l);
}

// Combine splits (weights via LDS) + overlap-add gather + crop -> crop (B,C,64)
__global__ __launch_bounds__(256) void overlap_kernel(
    const unsigned short* __restrict__ ogp, const float2* __restrict__ ml,
    float* __restrict__ crop) {
  __shared__ float w0s[64], w1s[64];
  int r = blockIdx.x;  // 256 = B*h*64 pixels
  int dim = threadIdx.x;
  int p = r & 63;
  int head = (r >> 6) & 1;
  int b = r >> 7;
  int bh = b * 2 + head;
  int y = p >> 3, x = p & 7;
  int py = y + TP, px = x + LP;
  int i0 = max(0, py - 7), i1 = min(7, py);
  int j0 = max(0, px - 7), j1 = min(7, px);
  int ni = i1 - i0 + 1, nj = j1 - j0 + 1, nq = ni * nj;
  if (dim < nq) {
    int iw = i0 + dim / nj, jw = j0 + dim % nj;
    int tok = (py - iw) * 8 + (px - jw);
    int q = (iw * 8 + jw) * 64 + tok;
    float2 a = ml[(size_t)bh * 4096 + q];
    float2 c = ml[(size_t)(4 + bh) * 4096 + q];
    float M = fmaxf(a.x, c.x);
    float e0 = __expf(a.x - M), e1 = __expf(c.x - M);
    float rr = 1.f / (a.y * e0 + c.y * e1);
    w0s[dim] = e0 * rr;
    w1s[dim] = e1 * rr;
  }
  __syncthreads();
  float s = 0.f;
  int t = 0;
  for (int iw = i0; iw <= i1; ++iw)
    for (int jw = j0; jw <= j1; ++jw, ++t) {
      int tok = (py - iw) * 8 + (px - jw);
      int q = (iw * 8 + jw) * 64 + tok;
      size_t e = ((size_t)bh * 4096 + q) * 256 + dim;
      s += w0s[t] * bf2f(ogp[e]) + w1s[t] * bf2f(ogp[(size_t)4 * LTOT * DH + e]);
    }
  float cnt = (float)nq;
  crop[((size_t)b * CC + head * DH + dim) * 64 + p] = s / (cnt + 1e-6f);
}

// out = x_feat + a * (Wproj @ crop + bproj)
__global__ __launch_bounds__(256) void final_kernel(
    const float* __restrict__ crop, const float* __restrict__ Wp,
    const float* __restrict__ bp, const float* __restrict__ x_feat,
    const float* __restrict__ pa, float* __restrict__ out) {
  int blocksPerB = CC >> 2;
  int b = blockIdx.x / blocksPerB;
  int ob = blockIdx.x - b * blocksPerB;
  int o = ob * 4 + (threadIdx.x >> 6);
  int p = threadIdx.x & 63;
  float a = 2.f / (1.f + __expf(-pa[0]));
  const float* xb = crop + (size_t)b * CC * 64;
  const float* wr = Wp + (size_t)o * CC;
  float acc = 0.f;
#pragma unroll 8
  for (int c = 0; c < CC; ++c) acc += wr[c] * xb[c * 64 + p];
  size_t oi = ((size_t)b * CC + o) * 64 + p;
  out[oi] = x_feat[oi] + a * (acc + bp[o]);
}

extern "C" void kernel_launch(void* const* d_in, const int* in_sizes, int n_in,
                              void* d_out, int out_size, void* d_ws, size_t ws_size,
                              hipStream_t stream) {
  const float* x_feat = (const float*)d_in[0];
  const float* z_feat = (const float*)d_in[1];
  const float* Wqkv = (const float*)d_in[2];
  const float* bqkv = (const float*)d_in[3];
  const float* Wqkz = (const float*)d_in[4];
  const float* bqkz = (const float*)d_in[5];
  const float* Wproj = (const float*)d_in[6];
  const float* bproj = (const float*)d_in[7];
  const float* pa = (const float*)d_in[8];
  const float* pbeta = (const float*)d_in[9];
  float* ws = (float*)d_ws;
  float* qkvx = ws;                                        // 196608 f
  float* qkz = ws + 196608;                                // 131072 f
  unsigned short* qgb = (unsigned short*)(ws + 327680);    // 2097152 f
  unsigned short* qgT = (unsigned short*)(ws + 2424832);   // 2097152 f
  unsigned short* ogp = (unsigned short*)(ws + 4521984);   // 4194304 f (2 splits)
  float2* ml = (float2*)(ws + 8716288);                    // 65536 f
  float* crop = ws;                                        // alias qkvx (dead after local_attn)
  float* out = (float*)d_out;

  conv_both_kernel<<<BB * (1536 / 4) + BB * (1024 / 4), 256, 0, stream>>>(
      x_feat, Wqkv, bqkv, qkvx, z_feat, Wqkz, bqkz, qkz);
  local_attn_kernel<<<256, 256, 0, stream>>>(qkvx, qkz, pbeta, qgb, qgT);
  gattn_mfma<<<512, 256, 0, stream>>>(qgb, qgT, ogp, ml);
  overlap_kernel<<<256, 256, 0, stream>>>(ogp, ml, crop);
  final_kernel<<<BB * (CC / 4), 256, 0, stream>>>(crop, Wproj, bproj, x_feat, pa, out);
}